// Round 9
// baseline (677.015 us; speedup 1.0000x reference)
//
#include <hip/hip_runtime.h>

#define NN 50000
#define EE 800000
#define DD 64
#define GG 512
#define HIDD 64
#define D2 128
#define NBLK 196          // ceil(NN/256)

// ---------------- zero: cnt_in[N], part[256] ----------------
__global__ void k_zero(int* __restrict__ cnt_in, int* __restrict__ part) {
    int i = blockIdx.x * blockDim.x + threadIdx.x;
    if (i < NN) cnt_in[i] = 0;
    if (i < 256) part[i] = 0;
}

// ---------------- in-degree count over edges (int atomics) ----------------
__global__ void k_count(const int* __restrict__ dst, int* __restrict__ cnt_in) {
    int e = blockIdx.x * blockDim.x + threadIdx.x;
    if (e < EE) atomicAdd(&cnt_in[dst[e]], 1);
}

// ---------------- scan step 1: per-block sums ----------------
__global__ void k_partial(const int* __restrict__ cnt_in, int* __restrict__ part) {
    __shared__ int s[256];
    int t = threadIdx.x, i = blockIdx.x * 256 + t;
    s[t] = (i < NN) ? cnt_in[i] : 0;
    __syncthreads();
    for (int off = 128; off > 0; off >>= 1) {
        if (t < off) s[t] += s[t + off];
        __syncthreads();
    }
    if (t == 0) part[blockIdx.x] = s[0];
}

// ---------------- scan step 2: exclusive scan of 256 partials ----------------
__global__ void k_scanp(int* __restrict__ part) {
    __shared__ int s[256];
    int t = threadIdx.x;
    int v = part[t];
    s[t] = v;
    __syncthreads();
    for (int off = 1; off < 256; off <<= 1) {
        int add = (t >= off) ? s[t - off] : 0;
        __syncthreads();
        s[t] += add;
        __syncthreads();
    }
    part[t] = s[t] - v;     // exclusive
}

// ---------------- scan step 3: rowptr + cursor ----------------
__global__ void k_rowptr(const int* __restrict__ cnt_in, const int* __restrict__ part,
                         int* __restrict__ rowptr, int* __restrict__ cursor) {
    __shared__ int s[256];
    int t = threadIdx.x, i = blockIdx.x * 256 + t;
    int v = (i < NN) ? cnt_in[i] : 0;
    s[t] = v;
    __syncthreads();
    for (int off = 1; off < 256; off <<= 1) {
        int add = (t >= off) ? s[t - off] : 0;
        __syncthreads();
        s[t] += add;
        __syncthreads();
    }
    int excl = s[t] - v + part[blockIdx.x];
    if (i <= NN) rowptr[i] = excl;          // rowptr[NN] == EE
    if (i < NN) cursor[i] = excl;
}

// ---------------- CSR fill: csr_src[pos] = src ----------------
__global__ void k_fill(const int* __restrict__ src, const int* __restrict__ dst,
                       int* __restrict__ cursor, int* __restrict__ csr) {
    int e = blockIdx.x * blockDim.x + threadIdx.x;
    if (e < EE) {
        int pos = atomicAdd(&cursor[dst[e]], 1);
        csr[pos] = src[e];
    }
}

// -- GEMM1 (reg-tiled, row-major LDS): t1s = (x@W1)*dinv; tile 128r x 64c ----
// per-thread 4r x 8c; all LDS ops are aligned float4; one sync.
__global__ __launch_bounds__(256) void k_gemm1(const float* __restrict__ x,
        const float* __restrict__ W1, const int* __restrict__ cnt_in,
        float* __restrict__ t1s) {
    __shared__ float As[128][68];   // x-tile row-major [r][k], pad 64->68
    __shared__ float Bs[DD][DD];    // W1 [k][c]
    int t = threadIdx.x;
    int row0 = blockIdx.x * 128;
    #pragma unroll
    for (int j = 0; j < 4; ++j) {               // W1: 1024 float4
        int id = t + j * 256;
        int k = id >> 4, c4 = (id & 15) * 4;
        *(float4*)&Bs[k][c4] = *(const float4*)&W1[k * DD + c4];
    }
    #pragma unroll
    for (int j = 0; j < 8; ++j) {               // x-tile: 2048 float4
        int id = t + j * 256;
        int r = id >> 4, k4 = (id & 15) * 4;
        int gr = row0 + r;
        float4 v = make_float4(0.f, 0.f, 0.f, 0.f);
        if (gr < NN) v = *(const float4*)&x[gr * DD + k4];
        *(float4*)&As[r][k4] = v;
    }
    __syncthreads();
    int rg = t >> 3, cg = t & 7;                // 32 rgs x 4 rows; 8 cgs x 8 cols
    int rbase = rg * 4, cbase = cg * 8;
    float acc[4][8] = {};
    #pragma unroll
    for (int kq = 0; kq < 16; ++kq) {
        float4 a0 = *(float4*)&As[rbase + 0][kq * 4];
        float4 a1 = *(float4*)&As[rbase + 1][kq * 4];
        float4 a2 = *(float4*)&As[rbase + 2][kq * 4];
        float4 a3 = *(float4*)&As[rbase + 3][kq * 4];
        float ar[4][4] = {{a0.x, a0.y, a0.z, a0.w}, {a1.x, a1.y, a1.z, a1.w},
                          {a2.x, a2.y, a2.z, a2.w}, {a3.x, a3.y, a3.z, a3.w}};
        #pragma unroll
        for (int kk = 0; kk < 4; ++kk) {
            float4 b0 = *(float4*)&Bs[kq * 4 + kk][cbase];
            float4 b1v = *(float4*)&Bs[kq * 4 + kk][cbase + 4];
            float bc[8] = {b0.x, b0.y, b0.z, b0.w, b1v.x, b1v.y, b1v.z, b1v.w};
            #pragma unroll
            for (int i = 0; i < 4; ++i) {
                #pragma unroll
                for (int c = 0; c < 8; ++c)
                    acc[i][c] += ar[i][kk] * bc[c];
            }
        }
    }
    #pragma unroll
    for (int i = 0; i < 4; ++i) {
        int gr = row0 + rbase + i;
        if (gr < NN) {
            float d = rsqrtf((float)cnt_in[gr] + 1.0f);
            float4 o0 = make_float4(acc[i][0] * d, acc[i][1] * d,
                                    acc[i][2] * d, acc[i][3] * d);
            float4 o1 = make_float4(acc[i][4] * d, acc[i][5] * d,
                                    acc[i][6] * d, acc[i][7] * d);
            *(float4*)&t1s[gr * DD + cbase] = o0;
            *(float4*)&t1s[gr * DD + cbase + 4] = o1;
        }
    }
}

// -------- aggregate layer 1: acc1[i] = t1s[i] + sum_{src->i} t1s[src] --------
__global__ __launch_bounds__(256) void k_agg1(const int* __restrict__ rowptr,
        const int* __restrict__ csr, const float* __restrict__ t1s,
        float* __restrict__ acc1) {
    int wid = (blockIdx.x * blockDim.x + threadIdx.x) >> 6;
    int c = threadIdx.x & 63;
    if (wid >= NN) return;
    int beg = rowptr[wid], end = rowptr[wid + 1];
    float a0 = t1s[wid * DD + c];       // self-loop term
    float a1 = 0.f, a2 = 0.f, a3 = 0.f;
    int e = beg;
    for (; e + 4 <= end; e += 4) {
        int s0 = csr[e], s1 = csr[e + 1], s2 = csr[e + 2], s3 = csr[e + 3];
        a0 += t1s[s0 * DD + c];
        a1 += t1s[s1 * DD + c];
        a2 += t1s[s2 * DD + c];
        a3 += t1s[s3 * DD + c];
    }
    for (; e < end; ++e) a0 += t1s[csr[e] * DD + c];
    acc1[wid * DD + c] = (a0 + a1) + (a2 + a3);
}

// -- GEMM2 (reg-tiled, row-major LDS): h=relu(dinv*acc1+b1); t2s=(h@W2)*dinv --
// tile 64r x 128c; per-thread 4r x 8c; one sync.
__global__ __launch_bounds__(256) void k_gemm2(const float* __restrict__ acc1,
        const float* __restrict__ W2, const float* __restrict__ b1,
        const int* __restrict__ cnt_in, float* __restrict__ t2s) {
    __shared__ float As[DD][68];    // h-tile row-major [r][k], pad 64->68
    __shared__ float Bs[DD][D2];    // W2 [k][c]
    int t = threadIdx.x;
    int row0 = blockIdx.x * 64;
    #pragma unroll
    for (int j = 0; j < 8; ++j) {               // W2: 2048 float4
        int id = t + j * 256;
        int k = id >> 5, c4 = (id & 31) * 4;
        *(float4*)&Bs[k][c4] = *(const float4*)&W2[k * D2 + c4];
    }
    #pragma unroll
    for (int j = 0; j < 4; ++j) {               // h-tile: 1024 float4, fused relu
        int id = t + j * 256;
        int r = id >> 4, k4 = (id & 15) * 4;
        int gr = row0 + r;
        float4 h = make_float4(0.f, 0.f, 0.f, 0.f);
        if (gr < NN) {
            float4 v  = *(const float4*)&acc1[gr * DD + k4];
            float4 bb = *(const float4*)&b1[k4];
            float d = rsqrtf((float)cnt_in[gr] + 1.0f);
            h.x = fmaxf(d * v.x + bb.x, 0.f);
            h.y = fmaxf(d * v.y + bb.y, 0.f);
            h.z = fmaxf(d * v.z + bb.z, 0.f);
            h.w = fmaxf(d * v.w + bb.w, 0.f);
        }
        *(float4*)&As[r][k4] = h;
    }
    __syncthreads();
    int rg = t >> 4, cg = t & 15;               // 16 rgs x 4 rows; 16 cgs x 8 cols
    int rbase = rg * 4, cbase = cg * 8;
    float acc[4][8] = {};
    #pragma unroll
    for (int kq = 0; kq < 16; ++kq) {
        float4 a0 = *(float4*)&As[rbase + 0][kq * 4];
        float4 a1 = *(float4*)&As[rbase + 1][kq * 4];
        float4 a2 = *(float4*)&As[rbase + 2][kq * 4];
        float4 a3 = *(float4*)&As[rbase + 3][kq * 4];
        float ar[4][4] = {{a0.x, a0.y, a0.z, a0.w}, {a1.x, a1.y, a1.z, a1.w},
                          {a2.x, a2.y, a2.z, a2.w}, {a3.x, a3.y, a3.z, a3.w}};
        #pragma unroll
        for (int kk = 0; kk < 4; ++kk) {
            float4 b0 = *(float4*)&Bs[kq * 4 + kk][cbase];
            float4 b1v = *(float4*)&Bs[kq * 4 + kk][cbase + 4];
            float bc[8] = {b0.x, b0.y, b0.z, b0.w, b1v.x, b1v.y, b1v.z, b1v.w};
            #pragma unroll
            for (int i = 0; i < 4; ++i) {
                #pragma unroll
                for (int c = 0; c < 8; ++c)
                    acc[i][c] += ar[i][kk] * bc[c];
            }
        }
    }
    #pragma unroll
    for (int i = 0; i < 4; ++i) {
        int gr = row0 + rbase + i;
        if (gr < NN) {
            float d = rsqrtf((float)cnt_in[gr] + 1.0f);
            float4 o0 = make_float4(acc[i][0] * d, acc[i][1] * d,
                                    acc[i][2] * d, acc[i][3] * d);
            float4 o1 = make_float4(acc[i][4] * d, acc[i][5] * d,
                                    acc[i][6] * d, acc[i][7] * d);
            *(float4*)&t2s[gr * D2 + cbase] = o0;
            *(float4*)&t2s[gr * D2 + cbase + 4] = o1;
        }
    }
}

// -------- aggregate layer 2 (float2 lanes): lane c handles channels 2c,2c+1 --
__global__ __launch_bounds__(256) void k_agg2(const int* __restrict__ rowptr,
        const int* __restrict__ csr, const float* __restrict__ t2s,
        float* __restrict__ acc2) {
    int wid = (blockIdx.x * blockDim.x + threadIdx.x) >> 6;
    int c = threadIdx.x & 63;
    if (wid >= NN) return;
    int beg = rowptr[wid], end = rowptr[wid + 1];
    float2 v = ((const float2*)&t2s[wid * D2])[c];   // self-loop term
    float a0 = v.x, b0 = v.y;
    float a1 = 0.f, b1 = 0.f, a2 = 0.f, b2 = 0.f, a3 = 0.f, b3 = 0.f;
    int e = beg;
    for (; e + 4 <= end; e += 4) {
        int s0 = csr[e], s1 = csr[e + 1], s2 = csr[e + 2], s3 = csr[e + 3];
        float2 u0 = ((const float2*)&t2s[s0 * D2])[c];
        float2 u1 = ((const float2*)&t2s[s1 * D2])[c];
        float2 u2 = ((const float2*)&t2s[s2 * D2])[c];
        float2 u3 = ((const float2*)&t2s[s3 * D2])[c];
        a0 += u0.x; b0 += u0.y;
        a1 += u1.x; b1 += u1.y;
        a2 += u2.x; b2 += u2.y;
        a3 += u3.x; b3 += u3.y;
    }
    for (; e < end; ++e) {
        float2 u = ((const float2*)&t2s[csr[e] * D2])[c];
        a0 += u.x; b0 += u.y;
    }
    float2 o;
    o.x = (a0 + a1) + (a2 + a3);
    o.y = (b0 + b1) + (b2 + b3);
    ((float2*)&acc2[wid * D2])[c] = o;
}

// ------- pool2: per-graph segmented reduce (batch is sorted) + fused FC ------
__global__ __launch_bounds__(128) void k_pool2(const float* __restrict__ acc2,
        const int* __restrict__ cnt_in, const float* __restrict__ b2,
        const int* __restrict__ batch, const float* __restrict__ Wfc,
        const float* __restrict__ bfc, float* __restrict__ out) {
    int g = blockIdx.x;
    int t = threadIdx.x;                 // 0..127 = channel
    int lo = 0, hi = NN;
    while (lo < hi) { int mid = (lo + hi) >> 1; if (batch[mid] < g) lo = mid + 1; else hi = mid; }
    int beg = lo;
    hi = NN;
    while (lo < hi) { int mid = (lo + hi) >> 1; if (batch[mid] < g + 1) lo = mid + 1; else hi = mid; }
    int end = lo;

    float s0 = 0.0f, s1 = 0.0f;
    int i = beg;
    for (; i + 2 <= end; i += 2) {
        float d0 = rsqrtf((float)cnt_in[i] + 1.0f);
        float d1 = rsqrtf((float)cnt_in[i + 1] + 1.0f);
        s0 += d0 * acc2[i * D2 + t];
        s1 += d1 * acc2[(i + 1) * D2 + t];
    }
    if (i < end)
        s0 += rsqrtf((float)cnt_in[i] + 1.0f) * acc2[i * D2 + t];

    int n = end - beg;
    float pooledv = (n > 0) ? ((s0 + s1) / (float)n + b2[t]) : 0.0f;

    __shared__ float pm[D2];
    pm[t] = pooledv;
    __syncthreads();
    if (t < HIDD) {
        float o = bfc[t];
        #pragma unroll
        for (int k = 0; k < D2; ++k)
            o += pm[k] * Wfc[k * HIDD + t];
        out[g * HIDD + t] = o;
    }
}

extern "C" void kernel_launch(void* const* d_in, const int* in_sizes, int n_in,
                              void* d_out, int out_size, void* d_ws, size_t ws_size,
                              hipStream_t stream) {
    const float* x     = (const float*)d_in[0];
    const int*   ei    = (const int*)  d_in[1];
    const int*   batch = (const int*)  d_in[2];
    const float* W1    = (const float*)d_in[3];
    const float* b1    = (const float*)d_in[4];
    const float* W2    = (const float*)d_in[5];
    const float* b2    = (const float*)d_in[6];
    const float* Wfc   = (const float*)d_in[7];
    const float* bfc   = (const float*)d_in[8];
    float* out = (float*)d_out;

    const int* src = ei;
    const int* dst = ei + EE;

    // ---- workspace layout ----
    float* fws    = (float*)d_ws;
    float* t1s    = fws;                        // NN*DD
    float* acc1   = t1s + NN * DD;              // NN*DD
    float* acc2   = t1s;                        // aliases t1s+acc1 (both dead)
    float* t2s    = acc1 + NN * DD;             // NN*D2
    int*   iws    = (int*)(t2s + NN * D2);
    int*   cnt_in = iws;                        // NN
    int*   rowptr = cnt_in + 50048;             // NN+1
    int*   cursor = rowptr + 50304;             // NN
    int*   part   = cursor + 50048;             // 256
    int*   csr    = part + 256;                 // EE
    // total ≈ 55 MB

    k_zero  <<<NBLK, 256, 0, stream>>>(cnt_in, part);
    k_count <<<(EE + 255) / 256, 256, 0, stream>>>(dst, cnt_in);
    k_partial<<<NBLK, 256, 0, stream>>>(cnt_in, part);
    k_scanp <<<1, 256, 0, stream>>>(part);
    k_rowptr<<<NBLK, 256, 0, stream>>>(cnt_in, part, rowptr, cursor);
    k_fill  <<<(EE + 255) / 256, 256, 0, stream>>>(src, dst, cursor, csr);
    k_gemm1 <<<(NN + 127) / 128, 256, 0, stream>>>(x, W1, cnt_in, t1s);
    k_agg1  <<<(NN * 64 + 255) / 256, 256, 0, stream>>>(rowptr, csr, t1s, acc1);
    k_gemm2 <<<(NN + 63) / 64, 256, 0, stream>>>(acc1, W2, b1, cnt_in, t2s);
    k_agg2  <<<(NN * 64 + 255) / 256, 256, 0, stream>>>(rowptr, csr, t2s, acc2);
    k_pool2 <<<GG, 128, 0, stream>>>(acc2, cnt_in, b2, batch, Wfc, bfc, out);
}

// Round 10
// 313.808 us; speedup vs baseline: 2.1574x; 2.1574x over previous
//
#include <hip/hip_runtime.h>

#define NN 50000
#define EE 800000
#define DD 64
#define GG 512
#define HIDD 64
#define D2 128
#define NBLK 196          // ceil(NN/256)

// ---------------- zero: cnt_in[N], part[256] ----------------
__global__ void k_zero(int* __restrict__ cnt_in, int* __restrict__ part) {
    int i = blockIdx.x * blockDim.x + threadIdx.x;
    if (i < NN) cnt_in[i] = 0;
    if (i < 256) part[i] = 0;
}

// ---------------- in-degree count over edges (int atomics) ----------------
__global__ void k_count(const int* __restrict__ dst, int* __restrict__ cnt_in) {
    int e = blockIdx.x * blockDim.x + threadIdx.x;
    if (e < EE) atomicAdd(&cnt_in[dst[e]], 1);
}

// ---------------- scan step 1: per-block sums ----------------
__global__ void k_partial(const int* __restrict__ cnt_in, int* __restrict__ part) {
    __shared__ int s[256];
    int t = threadIdx.x, i = blockIdx.x * 256 + t;
    s[t] = (i < NN) ? cnt_in[i] : 0;
    __syncthreads();
    for (int off = 128; off > 0; off >>= 1) {
        if (t < off) s[t] += s[t + off];
        __syncthreads();
    }
    if (t == 0) part[blockIdx.x] = s[0];
}

// ---------------- scan step 2: exclusive scan of 256 partials ----------------
__global__ void k_scanp(int* __restrict__ part) {
    __shared__ int s[256];
    int t = threadIdx.x;
    int v = part[t];
    s[t] = v;
    __syncthreads();
    for (int off = 1; off < 256; off <<= 1) {
        int add = (t >= off) ? s[t - off] : 0;
        __syncthreads();
        s[t] += add;
        __syncthreads();
    }
    part[t] = s[t] - v;     // exclusive
}

// ---------------- scan step 3: rowptr + cursor ----------------
__global__ void k_rowptr(const int* __restrict__ cnt_in, const int* __restrict__ part,
                         int* __restrict__ rowptr, int* __restrict__ cursor) {
    __shared__ int s[256];
    int t = threadIdx.x, i = blockIdx.x * 256 + t;
    int v = (i < NN) ? cnt_in[i] : 0;
    s[t] = v;
    __syncthreads();
    for (int off = 1; off < 256; off <<= 1) {
        int add = (t >= off) ? s[t - off] : 0;
        __syncthreads();
        s[t] += add;
        __syncthreads();
    }
    int excl = s[t] - v + part[blockIdx.x];
    if (i <= NN) rowptr[i] = excl;          // rowptr[NN] == EE
    if (i < NN) cursor[i] = excl;
}

// ---------------- CSR fill: csr_src[pos] = src ----------------
__global__ void k_fill(const int* __restrict__ src, const int* __restrict__ dst,
                       int* __restrict__ cursor, int* __restrict__ csr) {
    int e = blockIdx.x * blockDim.x + threadIdx.x;
    if (e < EE) {
        int pos = atomicAdd(&cursor[dst[e]], 1);
        csr[pos] = src[e];
    }
}

// -- GEMM1 (reg-tiled, named accumulators): t1s = (x@W1)*dinv; tile 128r x 64c
__global__ __launch_bounds__(256) void k_gemm1(const float* __restrict__ x,
        const float* __restrict__ W1, const int* __restrict__ cnt_in,
        float* __restrict__ t1s) {
    __shared__ float As[128][68];   // x-tile row-major [r][k], pad 64->68
    __shared__ float Bs[DD][DD];    // W1 [k][c]
    int t = threadIdx.x;
    int row0 = blockIdx.x * 128;
    #pragma unroll
    for (int j = 0; j < 4; ++j) {               // W1: 1024 float4
        int id = t + j * 256;
        int k = id >> 4, c4 = (id & 15) * 4;
        *(float4*)&Bs[k][c4] = *(const float4*)&W1[k * DD + c4];
    }
    #pragma unroll
    for (int j = 0; j < 8; ++j) {               // x-tile: 2048 float4
        int id = t + j * 256;
        int r = id >> 4, k4 = (id & 15) * 4;
        int gr = row0 + r;
        float4 v = make_float4(0.f, 0.f, 0.f, 0.f);
        if (gr < NN) v = *(const float4*)&x[gr * DD + k4];
        *(float4*)&As[r][k4] = v;
    }
    __syncthreads();
    int rbase = (t >> 3) * 4, cbase = (t & 7) * 8;
    float4 cL0 = make_float4(0.f,0.f,0.f,0.f), cH0 = cL0;
    float4 cL1 = cL0, cH1 = cL0, cL2 = cL0, cH2 = cL0, cL3 = cL0, cH3 = cL0;
    #pragma unroll 2
    for (int k = 0; k < DD; ++k) {
        float4 bL = *(const float4*)&Bs[k][cbase];
        float4 bH = *(const float4*)&Bs[k][cbase + 4];
        float a0 = As[rbase + 0][k];
        float a1 = As[rbase + 1][k];
        float a2 = As[rbase + 2][k];
        float a3 = As[rbase + 3][k];
        cL0 += bL * a0;  cH0 += bH * a0;
        cL1 += bL * a1;  cH1 += bH * a1;
        cL2 += bL * a2;  cH2 += bH * a2;
        cL3 += bL * a3;  cH3 += bH * a3;
    }
    int gr0 = row0 + rbase;
    if (gr0 + 0 < NN) { float d = rsqrtf((float)cnt_in[gr0 + 0] + 1.0f);
        *(float4*)&t1s[(gr0 + 0) * DD + cbase] = cL0 * d;
        *(float4*)&t1s[(gr0 + 0) * DD + cbase + 4] = cH0 * d; }
    if (gr0 + 1 < NN) { float d = rsqrtf((float)cnt_in[gr0 + 1] + 1.0f);
        *(float4*)&t1s[(gr0 + 1) * DD + cbase] = cL1 * d;
        *(float4*)&t1s[(gr0 + 1) * DD + cbase + 4] = cH1 * d; }
    if (gr0 + 2 < NN) { float d = rsqrtf((float)cnt_in[gr0 + 2] + 1.0f);
        *(float4*)&t1s[(gr0 + 2) * DD + cbase] = cL2 * d;
        *(float4*)&t1s[(gr0 + 2) * DD + cbase + 4] = cH2 * d; }
    if (gr0 + 3 < NN) { float d = rsqrtf((float)cnt_in[gr0 + 3] + 1.0f);
        *(float4*)&t1s[(gr0 + 3) * DD + cbase] = cL3 * d;
        *(float4*)&t1s[(gr0 + 3) * DD + cbase + 4] = cH3 * d; }
}

// -------- aggregate layer 1: acc1[i] = t1s[i] + sum_{src->i} t1s[src] --------
__global__ __launch_bounds__(256) void k_agg1(const int* __restrict__ rowptr,
        const int* __restrict__ csr, const float* __restrict__ t1s,
        float* __restrict__ acc1) {
    int wid = (blockIdx.x * blockDim.x + threadIdx.x) >> 6;
    int c = threadIdx.x & 63;
    if (wid >= NN) return;
    int beg = rowptr[wid], end = rowptr[wid + 1];
    float a0 = t1s[wid * DD + c];       // self-loop term
    float a1 = 0.f, a2 = 0.f, a3 = 0.f;
    int e = beg;
    for (; e + 4 <= end; e += 4) {
        int s0 = csr[e], s1 = csr[e + 1], s2 = csr[e + 2], s3 = csr[e + 3];
        a0 += t1s[s0 * DD + c];
        a1 += t1s[s1 * DD + c];
        a2 += t1s[s2 * DD + c];
        a3 += t1s[s3 * DD + c];
    }
    for (; e < end; ++e) a0 += t1s[csr[e] * DD + c];
    acc1[wid * DD + c] = (a0 + a1) + (a2 + a3);
}

// -- GEMM2 (reg-tiled, named accumulators): h=relu(dinv*acc1+b1); t2s=(h@W2)*dinv
__global__ __launch_bounds__(256) void k_gemm2(const float* __restrict__ acc1,
        const float* __restrict__ W2, const float* __restrict__ b1,
        const int* __restrict__ cnt_in, float* __restrict__ t2s) {
    __shared__ float As[DD][68];    // h-tile row-major [r][k], pad 64->68
    __shared__ float Bs[DD][D2];    // W2 [k][c]
    int t = threadIdx.x;
    int row0 = blockIdx.x * 64;
    #pragma unroll
    for (int j = 0; j < 8; ++j) {               // W2: 2048 float4
        int id = t + j * 256;
        int k = id >> 5, c4 = (id & 31) * 4;
        *(float4*)&Bs[k][c4] = *(const float4*)&W2[k * D2 + c4];
    }
    #pragma unroll
    for (int j = 0; j < 4; ++j) {               // h-tile: 1024 float4, fused relu
        int id = t + j * 256;
        int r = id >> 4, k4 = (id & 15) * 4;
        int gr = row0 + r;
        float4 h = make_float4(0.f, 0.f, 0.f, 0.f);
        if (gr < NN) {
            float4 v  = *(const float4*)&acc1[gr * DD + k4];
            float4 bb = *(const float4*)&b1[k4];
            float d = rsqrtf((float)cnt_in[gr] + 1.0f);
            h.x = fmaxf(d * v.x + bb.x, 0.f);
            h.y = fmaxf(d * v.y + bb.y, 0.f);
            h.z = fmaxf(d * v.z + bb.z, 0.f);
            h.w = fmaxf(d * v.w + bb.w, 0.f);
        }
        *(float4*)&As[r][k4] = h;
    }
    __syncthreads();
    int rbase = (t >> 4) * 4, cbase = (t & 15) * 8;
    float4 cL0 = make_float4(0.f,0.f,0.f,0.f), cH0 = cL0;
    float4 cL1 = cL0, cH1 = cL0, cL2 = cL0, cH2 = cL0, cL3 = cL0, cH3 = cL0;
    #pragma unroll 2
    for (int k = 0; k < DD; ++k) {
        float4 bL = *(const float4*)&Bs[k][cbase];
        float4 bH = *(const float4*)&Bs[k][cbase + 4];
        float a0 = As[rbase + 0][k];
        float a1 = As[rbase + 1][k];
        float a2 = As[rbase + 2][k];
        float a3 = As[rbase + 3][k];
        cL0 += bL * a0;  cH0 += bH * a0;
        cL1 += bL * a1;  cH1 += bH * a1;
        cL2 += bL * a2;  cH2 += bH * a2;
        cL3 += bL * a3;  cH3 += bH * a3;
    }
    int gr0 = row0 + rbase;
    if (gr0 + 0 < NN) { float d = rsqrtf((float)cnt_in[gr0 + 0] + 1.0f);
        *(float4*)&t2s[(gr0 + 0) * D2 + cbase] = cL0 * d;
        *(float4*)&t2s[(gr0 + 0) * D2 + cbase + 4] = cH0 * d; }
    if (gr0 + 1 < NN) { float d = rsqrtf((float)cnt_in[gr0 + 1] + 1.0f);
        *(float4*)&t2s[(gr0 + 1) * D2 + cbase] = cL1 * d;
        *(float4*)&t2s[(gr0 + 1) * D2 + cbase + 4] = cH1 * d; }
    if (gr0 + 2 < NN) { float d = rsqrtf((float)cnt_in[gr0 + 2] + 1.0f);
        *(float4*)&t2s[(gr0 + 2) * D2 + cbase] = cL2 * d;
        *(float4*)&t2s[(gr0 + 2) * D2 + cbase + 4] = cH2 * d; }
    if (gr0 + 3 < NN) { float d = rsqrtf((float)cnt_in[gr0 + 3] + 1.0f);
        *(float4*)&t2s[(gr0 + 3) * D2 + cbase] = cL3 * d;
        *(float4*)&t2s[(gr0 + 3) * D2 + cbase + 4] = cH3 * d; }
}

// -------- aggregate layer 2 (float2 lanes): lane c handles channels 2c,2c+1 --
__global__ __launch_bounds__(256) void k_agg2(const int* __restrict__ rowptr,
        const int* __restrict__ csr, const float* __restrict__ t2s,
        float* __restrict__ acc2) {
    int wid = (blockIdx.x * blockDim.x + threadIdx.x) >> 6;
    int c = threadIdx.x & 63;
    if (wid >= NN) return;
    int beg = rowptr[wid], end = rowptr[wid + 1];
    float2 v = ((const float2*)&t2s[wid * D2])[c];   // self-loop term
    float a0 = v.x, b0 = v.y;
    float a1 = 0.f, b1 = 0.f, a2 = 0.f, b2 = 0.f, a3 = 0.f, b3 = 0.f;
    int e = beg;
    for (; e + 4 <= end; e += 4) {
        int s0 = csr[e], s1 = csr[e + 1], s2 = csr[e + 2], s3 = csr[e + 3];
        float2 u0 = ((const float2*)&t2s[s0 * D2])[c];
        float2 u1 = ((const float2*)&t2s[s1 * D2])[c];
        float2 u2 = ((const float2*)&t2s[s2 * D2])[c];
        float2 u3 = ((const float2*)&t2s[s3 * D2])[c];
        a0 += u0.x; b0 += u0.y;
        a1 += u1.x; b1 += u1.y;
        a2 += u2.x; b2 += u2.y;
        a3 += u3.x; b3 += u3.y;
    }
    for (; e < end; ++e) {
        float2 u = ((const float2*)&t2s[csr[e] * D2])[c];
        a0 += u.x; b0 += u.y;
    }
    float2 o;
    o.x = (a0 + a1) + (a2 + a3);
    o.y = (b0 + b1) + (b2 + b3);
    ((float2*)&acc2[wid * D2])[c] = o;
}

// ------- pool2: per-graph segmented reduce (batch is sorted) + fused FC ------
__global__ __launch_bounds__(128) void k_pool2(const float* __restrict__ acc2,
        const int* __restrict__ cnt_in, const float* __restrict__ b2,
        const int* __restrict__ batch, const float* __restrict__ Wfc,
        const float* __restrict__ bfc, float* __restrict__ out) {
    int g = blockIdx.x;
    int t = threadIdx.x;                 // 0..127 = channel
    int lo = 0, hi = NN;
    while (lo < hi) { int mid = (lo + hi) >> 1; if (batch[mid] < g) lo = mid + 1; else hi = mid; }
    int beg = lo;
    hi = NN;
    while (lo < hi) { int mid = (lo + hi) >> 1; if (batch[mid] < g + 1) lo = mid + 1; else hi = mid; }
    int end = lo;

    float s0 = 0.0f, s1 = 0.0f;
    int i = beg;
    for (; i + 2 <= end; i += 2) {
        float d0 = rsqrtf((float)cnt_in[i] + 1.0f);
        float d1 = rsqrtf((float)cnt_in[i + 1] + 1.0f);
        s0 += d0 * acc2[i * D2 + t];
        s1 += d1 * acc2[(i + 1) * D2 + t];
    }
    if (i < end)
        s0 += rsqrtf((float)cnt_in[i] + 1.0f) * acc2[i * D2 + t];

    int n = end - beg;
    float pooledv = (n > 0) ? ((s0 + s1) / (float)n + b2[t]) : 0.0f;

    __shared__ float pm[D2];
    pm[t] = pooledv;
    __syncthreads();
    if (t < HIDD) {
        float o = bfc[t];
        #pragma unroll
        for (int k = 0; k < D2; ++k)
            o += pm[k] * Wfc[k * HIDD + t];
        out[g * HIDD + t] = o;
    }
}

extern "C" void kernel_launch(void* const* d_in, const int* in_sizes, int n_in,
                              void* d_out, int out_size, void* d_ws, size_t ws_size,
                              hipStream_t stream) {
    const float* x     = (const float*)d_in[0];
    const int*   ei    = (const int*)  d_in[1];
    const int*   batch = (const int*)  d_in[2];
    const float* W1    = (const float*)d_in[3];
    const float* b1    = (const float*)d_in[4];
    const float* W2    = (const float*)d_in[5];
    const float* b2    = (const float*)d_in[6];
    const float* Wfc   = (const float*)d_in[7];
    const float* bfc   = (const float*)d_in[8];
    float* out = (float*)d_out;

    const int* src = ei;
    const int* dst = ei + EE;

    // ---- workspace layout ----
    float* fws    = (float*)d_ws;
    float* t1s    = fws;                        // NN*DD
    float* acc1   = t1s + NN * DD;              // NN*DD
    float* acc2   = t1s;                        // aliases t1s+acc1 (both dead)
    float* t2s    = acc1 + NN * DD;             // NN*D2
    int*   iws    = (int*)(t2s + NN * D2);
    int*   cnt_in = iws;                        // NN
    int*   rowptr = cnt_in + 50048;             // NN+1
    int*   cursor = rowptr + 50304;             // NN
    int*   part   = cursor + 50048;             // 256
    int*   csr    = part + 256;                 // EE
    // total ≈ 55 MB

    k_zero  <<<NBLK, 256, 0, stream>>>(cnt_in, part);
    k_count <<<(EE + 255) / 256, 256, 0, stream>>>(dst, cnt_in);
    k_partial<<<NBLK, 256, 0, stream>>>(cnt_in, part);
    k_scanp <<<1, 256, 0, stream>>>(part);
    k_rowptr<<<NBLK, 256, 0, stream>>>(cnt_in, part, rowptr, cursor);
    k_fill  <<<(EE + 255) / 256, 256, 0, stream>>>(src, dst, cursor, csr);
    k_gemm1 <<<(NN + 127) / 128, 256, 0, stream>>>(x, W1, cnt_in, t1s);
    k_agg1  <<<(NN * 64 + 255) / 256, 256, 0, stream>>>(rowptr, csr, t1s, acc1);
    k_gemm2 <<<(NN + 63) / 64, 256, 0, stream>>>(acc1, W2, b1, cnt_in, t2s);
    k_agg2  <<<(NN * 64 + 255) / 256, 256, 0, stream>>>(rowptr, csr, t2s, acc2);
    k_pool2 <<<GG, 128, 0, stream>>>(acc2, cnt_in, b2, batch, Wfc, bfc, out);
}

// Round 11
// 297.340 us; speedup vs baseline: 2.2769x; 1.0554x over previous
//
#include <hip/hip_runtime.h>

#define NN 50000
#define EE 800000
#define DD 64
#define GG 512
#define HIDD 64
#define D2 128
#define NBLK 196          // ceil(NN/256)

// ---------------- zero: cnt_in[N], part[256] ----------------
__global__ void k_zero(int* __restrict__ cnt_in, int* __restrict__ part) {
    int i = blockIdx.x * blockDim.x + threadIdx.x;
    if (i < NN) cnt_in[i] = 0;
    if (i < 256) part[i] = 0;
}

// ---------------- in-degree count over edges (int atomics) ----------------
__global__ void k_count(const int* __restrict__ dst, int* __restrict__ cnt_in) {
    int e = blockIdx.x * blockDim.x + threadIdx.x;
    if (e < EE) atomicAdd(&cnt_in[dst[e]], 1);
}

// ---------------- scan step 1: per-block sums ----------------
__global__ void k_partial(const int* __restrict__ cnt_in, int* __restrict__ part) {
    __shared__ int s[256];
    int t = threadIdx.x, i = blockIdx.x * 256 + t;
    s[t] = (i < NN) ? cnt_in[i] : 0;
    __syncthreads();
    for (int off = 128; off > 0; off >>= 1) {
        if (t < off) s[t] += s[t + off];
        __syncthreads();
    }
    if (t == 0) part[blockIdx.x] = s[0];
}

// ---------------- scan step 2: exclusive scan of 256 partials ----------------
__global__ void k_scanp(int* __restrict__ part) {
    __shared__ int s[256];
    int t = threadIdx.x;
    int v = part[t];
    s[t] = v;
    __syncthreads();
    for (int off = 1; off < 256; off <<= 1) {
        int add = (t >= off) ? s[t - off] : 0;
        __syncthreads();
        s[t] += add;
        __syncthreads();
    }
    part[t] = s[t] - v;     // exclusive
}

// ---------------- scan step 3: rowptr + cursor ----------------
__global__ void k_rowptr(const int* __restrict__ cnt_in, const int* __restrict__ part,
                         int* __restrict__ rowptr, int* __restrict__ cursor) {
    __shared__ int s[256];
    int t = threadIdx.x, i = blockIdx.x * 256 + t;
    int v = (i < NN) ? cnt_in[i] : 0;
    s[t] = v;
    __syncthreads();
    for (int off = 1; off < 256; off <<= 1) {
        int add = (t >= off) ? s[t - off] : 0;
        __syncthreads();
        s[t] += add;
        __syncthreads();
    }
    int excl = s[t] - v + part[blockIdx.x];
    if (i <= NN) rowptr[i] = excl;          // rowptr[NN] == EE
    if (i < NN) cursor[i] = excl;
}

// ---------------- CSR fill: csr_src[pos] = src ----------------
__global__ void k_fill(const int* __restrict__ src, const int* __restrict__ dst,
                       int* __restrict__ cursor, int* __restrict__ csr) {
    int e = blockIdx.x * blockDim.x + threadIdx.x;
    if (e < EE) {
        int pos = atomicAdd(&cursor[dst[e]], 1);
        csr[pos] = src[e];
    }
}

// -- GEMM1 (reg-tiled, named accumulators): t1s = (x@W1)*dinv; tile 128r x 64c
__global__ __launch_bounds__(256) void k_gemm1(const float* __restrict__ x,
        const float* __restrict__ W1, const int* __restrict__ cnt_in,
        float* __restrict__ t1s) {
    __shared__ float As[128][68];   // x-tile row-major [r][k], pad 64->68
    __shared__ float Bs[DD][DD];    // W1 [k][c]
    int t = threadIdx.x;
    int row0 = blockIdx.x * 128;
    #pragma unroll
    for (int j = 0; j < 4; ++j) {               // W1: 1024 float4
        int id = t + j * 256;
        int k = id >> 4, c4 = (id & 15) * 4;
        *(float4*)&Bs[k][c4] = *(const float4*)&W1[k * DD + c4];
    }
    #pragma unroll
    for (int j = 0; j < 8; ++j) {               // x-tile: 2048 float4
        int id = t + j * 256;
        int r = id >> 4, k4 = (id & 15) * 4;
        int gr = row0 + r;
        float4 v = make_float4(0.f, 0.f, 0.f, 0.f);
        if (gr < NN) v = *(const float4*)&x[gr * DD + k4];
        *(float4*)&As[r][k4] = v;
    }
    __syncthreads();
    int rbase = (t >> 3) * 4, cbase = (t & 7) * 8;
    float4 cL0 = make_float4(0.f,0.f,0.f,0.f), cH0 = cL0;
    float4 cL1 = cL0, cH1 = cL0, cL2 = cL0, cH2 = cL0, cL3 = cL0, cH3 = cL0;
    #pragma unroll 2
    for (int k = 0; k < DD; ++k) {
        float4 bL = *(const float4*)&Bs[k][cbase];
        float4 bH = *(const float4*)&Bs[k][cbase + 4];
        float a0 = As[rbase + 0][k];
        float a1 = As[rbase + 1][k];
        float a2 = As[rbase + 2][k];
        float a3 = As[rbase + 3][k];
        cL0 += bL * a0;  cH0 += bH * a0;
        cL1 += bL * a1;  cH1 += bH * a1;
        cL2 += bL * a2;  cH2 += bH * a2;
        cL3 += bL * a3;  cH3 += bH * a3;
    }
    int gr0 = row0 + rbase;
    if (gr0 + 0 < NN) { float d = rsqrtf((float)cnt_in[gr0 + 0] + 1.0f);
        *(float4*)&t1s[(gr0 + 0) * DD + cbase] = cL0 * d;
        *(float4*)&t1s[(gr0 + 0) * DD + cbase + 4] = cH0 * d; }
    if (gr0 + 1 < NN) { float d = rsqrtf((float)cnt_in[gr0 + 1] + 1.0f);
        *(float4*)&t1s[(gr0 + 1) * DD + cbase] = cL1 * d;
        *(float4*)&t1s[(gr0 + 1) * DD + cbase + 4] = cH1 * d; }
    if (gr0 + 2 < NN) { float d = rsqrtf((float)cnt_in[gr0 + 2] + 1.0f);
        *(float4*)&t1s[(gr0 + 2) * DD + cbase] = cL2 * d;
        *(float4*)&t1s[(gr0 + 2) * DD + cbase + 4] = cH2 * d; }
    if (gr0 + 3 < NN) { float d = rsqrtf((float)cnt_in[gr0 + 3] + 1.0f);
        *(float4*)&t1s[(gr0 + 3) * DD + cbase] = cL3 * d;
        *(float4*)&t1s[(gr0 + 3) * DD + cbase + 4] = cH3 * d; }
}

// -- agg1 + fused conv1 epilogue: u = dinv * relu(dinv * (t1s[i]+Σ t1s[src]) + b1)
__global__ __launch_bounds__(256) void k_agg1(const int* __restrict__ rowptr,
        const int* __restrict__ csr, const float* __restrict__ t1s,
        const int* __restrict__ cnt_in, const float* __restrict__ b1,
        float* __restrict__ u) {
    int wid = (blockIdx.x * blockDim.x + threadIdx.x) >> 6;
    int c = threadIdx.x & 63;
    if (wid >= NN) return;
    int beg = rowptr[wid], end = rowptr[wid + 1];
    float a0 = t1s[wid * DD + c];       // self-loop term
    float a1 = 0.f, a2 = 0.f, a3 = 0.f;
    int e = beg;
    for (; e + 4 <= end; e += 4) {
        int s0 = csr[e], s1 = csr[e + 1], s2 = csr[e + 2], s3 = csr[e + 3];
        a0 += t1s[s0 * DD + c];
        a1 += t1s[s1 * DD + c];
        a2 += t1s[s2 * DD + c];
        a3 += t1s[s3 * DD + c];
    }
    for (; e < end; ++e) a0 += t1s[csr[e] * DD + c];
    float d = rsqrtf((float)cnt_in[wid] + 1.0f);
    float h = fmaxf(d * ((a0 + a1) + (a2 + a3)) + b1[c], 0.0f);
    u[wid * DD + c] = d * h;
}

// -- agg2 (64-ch gather on u): w = dinv * (u[i] + Σ u[src]) --
__global__ __launch_bounds__(256) void k_agg2(const int* __restrict__ rowptr,
        const int* __restrict__ csr, const float* __restrict__ u,
        const int* __restrict__ cnt_in, float* __restrict__ w) {
    int wid = (blockIdx.x * blockDim.x + threadIdx.x) >> 6;
    int c = threadIdx.x & 63;
    if (wid >= NN) return;
    int beg = rowptr[wid], end = rowptr[wid + 1];
    float a0 = u[wid * DD + c];         // self-loop term
    float a1 = 0.f, a2 = 0.f, a3 = 0.f;
    int e = beg;
    for (; e + 4 <= end; e += 4) {
        int s0 = csr[e], s1 = csr[e + 1], s2 = csr[e + 2], s3 = csr[e + 3];
        a0 += u[s0 * DD + c];
        a1 += u[s1 * DD + c];
        a2 += u[s2 * DD + c];
        a3 += u[s3 * DD + c];
    }
    for (; e < end; ++e) a0 += u[csr[e] * DD + c];
    float d = rsqrtf((float)cnt_in[wid] + 1.0f);
    w[wid * DD + c] = d * ((a0 + a1) + (a2 + a3));
}

// -- GEMM2 (pure, reg-tiled): acc2 = w@W2 + b2; tile 64r x 128c --
__global__ __launch_bounds__(256) void k_gemm2(const float* __restrict__ w,
        const float* __restrict__ W2, const float* __restrict__ b2,
        float* __restrict__ acc2) {
    __shared__ float As[DD][68];    // w-tile row-major [r][k], pad 64->68
    __shared__ float Bs[DD][D2];    // W2 [k][c]
    int t = threadIdx.x;
    int row0 = blockIdx.x * 64;
    #pragma unroll
    for (int j = 0; j < 8; ++j) {               // W2: 2048 float4
        int id = t + j * 256;
        int k = id >> 5, c4 = (id & 31) * 4;
        *(float4*)&Bs[k][c4] = *(const float4*)&W2[k * D2 + c4];
    }
    #pragma unroll
    for (int j = 0; j < 4; ++j) {               // w-tile: 1024 float4
        int id = t + j * 256;
        int r = id >> 4, k4 = (id & 15) * 4;
        int gr = row0 + r;
        float4 v = make_float4(0.f, 0.f, 0.f, 0.f);
        if (gr < NN) v = *(const float4*)&w[gr * DD + k4];
        *(float4*)&As[r][k4] = v;
    }
    __syncthreads();
    int rbase = (t >> 4) * 4, cbase = (t & 15) * 8;
    float4 cL0 = make_float4(0.f,0.f,0.f,0.f), cH0 = cL0;
    float4 cL1 = cL0, cH1 = cL0, cL2 = cL0, cH2 = cL0, cL3 = cL0, cH3 = cL0;
    #pragma unroll 2
    for (int k = 0; k < DD; ++k) {
        float4 bL = *(const float4*)&Bs[k][cbase];
        float4 bH = *(const float4*)&Bs[k][cbase + 4];
        float a0 = As[rbase + 0][k];
        float a1 = As[rbase + 1][k];
        float a2 = As[rbase + 2][k];
        float a3 = As[rbase + 3][k];
        cL0 += bL * a0;  cH0 += bH * a0;
        cL1 += bL * a1;  cH1 += bH * a1;
        cL2 += bL * a2;  cH2 += bH * a2;
        cL3 += bL * a3;  cH3 += bH * a3;
    }
    float4 b2L = *(const float4*)&b2[cbase];
    float4 b2H = *(const float4*)&b2[cbase + 4];
    int gr0 = row0 + rbase;
    if (gr0 + 0 < NN) {
        *(float4*)&acc2[(gr0 + 0) * D2 + cbase] = cL0 + b2L;
        *(float4*)&acc2[(gr0 + 0) * D2 + cbase + 4] = cH0 + b2H; }
    if (gr0 + 1 < NN) {
        *(float4*)&acc2[(gr0 + 1) * D2 + cbase] = cL1 + b2L;
        *(float4*)&acc2[(gr0 + 1) * D2 + cbase + 4] = cH1 + b2H; }
    if (gr0 + 2 < NN) {
        *(float4*)&acc2[(gr0 + 2) * D2 + cbase] = cL2 + b2L;
        *(float4*)&acc2[(gr0 + 2) * D2 + cbase + 4] = cH2 + b2H; }
    if (gr0 + 3 < NN) {
        *(float4*)&acc2[(gr0 + 3) * D2 + cbase] = cL3 + b2L;
        *(float4*)&acc2[(gr0 + 3) * D2 + cbase + 4] = cH3 + b2H; }
}

// ------- pool2: per-graph mean (batch sorted; rows include b2) + fused FC ----
__global__ __launch_bounds__(128) void k_pool2(const float* __restrict__ acc2,
        const int* __restrict__ batch, const float* __restrict__ Wfc,
        const float* __restrict__ bfc, float* __restrict__ out) {
    int g = blockIdx.x;
    int t = threadIdx.x;                 // 0..127 = channel
    int lo = 0, hi = NN;
    while (lo < hi) { int mid = (lo + hi) >> 1; if (batch[mid] < g) lo = mid + 1; else hi = mid; }
    int beg = lo;
    hi = NN;
    while (lo < hi) { int mid = (lo + hi) >> 1; if (batch[mid] < g + 1) lo = mid + 1; else hi = mid; }
    int end = lo;

    float s0 = 0.0f, s1 = 0.0f;
    int i = beg;
    for (; i + 2 <= end; i += 2) {
        s0 += acc2[i * D2 + t];
        s1 += acc2[(i + 1) * D2 + t];
    }
    if (i < end) s0 += acc2[i * D2 + t];

    int n = end - beg;
    float pooledv = (n > 0) ? ((s0 + s1) / (float)n) : 0.0f;

    __shared__ float pm[D2];
    pm[t] = pooledv;
    __syncthreads();
    if (t < HIDD) {
        float o = bfc[t];
        #pragma unroll
        for (int k = 0; k < D2; ++k)
            o += pm[k] * Wfc[k * HIDD + t];
        out[g * HIDD + t] = o;
    }
}

extern "C" void kernel_launch(void* const* d_in, const int* in_sizes, int n_in,
                              void* d_out, int out_size, void* d_ws, size_t ws_size,
                              hipStream_t stream) {
    const float* x     = (const float*)d_in[0];
    const int*   ei    = (const int*)  d_in[1];
    const int*   batch = (const int*)  d_in[2];
    const float* W1    = (const float*)d_in[3];
    const float* b1    = (const float*)d_in[4];
    const float* W2    = (const float*)d_in[5];
    const float* b2    = (const float*)d_in[6];
    const float* Wfc   = (const float*)d_in[7];
    const float* bfc   = (const float*)d_in[8];
    float* out = (float*)d_out;

    const int* src = ei;
    const int* dst = ei + EE;

    // ---- workspace layout ----
    float* fws  = (float*)d_ws;
    float* t1s  = fws;                          // NN*DD
    float* u    = t1s + NN * DD;                // NN*DD
    float* w    = u + NN * DD;                  // NN*DD
    float* acc2 = t1s;                          // aliases t1s+u (both dead), NN*D2
    int*   iws    = (int*)(w + NN * DD);
    int*   cnt_in = iws;                        // NN
    int*   rowptr = cnt_in + 50048;             // NN+1
    int*   cursor = rowptr + 50304;             // NN
    int*   part   = cursor + 50048;             // 256
    int*   csr    = part + 256;                 // EE
    // total ≈ 42 MB

    k_zero  <<<NBLK, 256, 0, stream>>>(cnt_in, part);
    k_count <<<(EE + 255) / 256, 256, 0, stream>>>(dst, cnt_in);
    k_partial<<<NBLK, 256, 0, stream>>>(cnt_in, part);
    k_scanp <<<1, 256, 0, stream>>>(part);
    k_rowptr<<<NBLK, 256, 0, stream>>>(cnt_in, part, rowptr, cursor);
    k_fill  <<<(EE + 255) / 256, 256, 0, stream>>>(src, dst, cursor, csr);
    k_gemm1 <<<(NN + 127) / 128, 256, 0, stream>>>(x, W1, cnt_in, t1s);
    k_agg1  <<<(NN * 64 + 255) / 256, 256, 0, stream>>>(rowptr, csr, t1s, cnt_in, b1, u);
    k_agg2  <<<(NN * 64 + 255) / 256, 256, 0, stream>>>(rowptr, csr, u, cnt_in, w);
    k_gemm2 <<<(NN + 63) / 64, 256, 0, stream>>>(w, W2, b2, acc2);
    k_pool2 <<<GG, 128, 0, stream>>>(acc2, batch, Wfc, bfc, out);
}

// Round 13
// 237.021 us; speedup vs baseline: 2.8563x; 1.2545x over previous
//
#include <hip/hip_runtime.h>
#include <hip/hip_fp16.h>

#define NN 50000
#define EE 800000
#define DD 64
#define GG 512
#define HIDD 64
#define D2 128
#define NBLK 196          // ceil(NN/256)

__device__ inline __half2 mk2(float a, float b) {
    __half2 h; h.x = __float2half_rn(a); h.y = __float2half_rn(b); return h;
}

// ---------------- zero: cnt_in[N], part[256] ----------------
__global__ void k_zero(int* __restrict__ cnt_in, int* __restrict__ part) {
    int i = blockIdx.x * blockDim.x + threadIdx.x;
    if (i < NN) cnt_in[i] = 0;
    if (i < 256) part[i] = 0;
}

// ------ count + rank: one atomic pass; rank stored coalesced ------
__global__ void k_count_rank(const int* __restrict__ dst, int* __restrict__ cnt_in,
                             int* __restrict__ rank) {
    int e = blockIdx.x * blockDim.x + threadIdx.x;
    if (e < EE) rank[e] = atomicAdd(&cnt_in[dst[e]], 1);
}

// ---------------- scan step 1: per-block sums ----------------
__global__ void k_partial(const int* __restrict__ cnt_in, int* __restrict__ part) {
    __shared__ int s[256];
    int t = threadIdx.x, i = blockIdx.x * 256 + t;
    s[t] = (i < NN) ? cnt_in[i] : 0;
    __syncthreads();
    for (int off = 128; off > 0; off >>= 1) {
        if (t < off) s[t] += s[t + off];
        __syncthreads();
    }
    if (t == 0) part[blockIdx.x] = s[0];
}

// ---------------- scan step 2: exclusive scan of 256 partials ----------------
__global__ void k_scanp(int* __restrict__ part) {
    __shared__ int s[256];
    int t = threadIdx.x;
    int v = part[t];
    s[t] = v;
    __syncthreads();
    for (int off = 1; off < 256; off <<= 1) {
        int add = (t >= off) ? s[t - off] : 0;
        __syncthreads();
        s[t] += add;
        __syncthreads();
    }
    part[t] = s[t] - v;     // exclusive
}

// ---------------- scan step 3: rowptr ----------------
__global__ void k_rowptr(const int* __restrict__ cnt_in, const int* __restrict__ part,
                         int* __restrict__ rowptr) {
    __shared__ int s[256];
    int t = threadIdx.x, i = blockIdx.x * 256 + t;
    int v = (i < NN) ? cnt_in[i] : 0;
    s[t] = v;
    __syncthreads();
    for (int off = 1; off < 256; off <<= 1) {
        int add = (t >= off) ? s[t - off] : 0;
        __syncthreads();
        s[t] += add;
        __syncthreads();
    }
    int excl = s[t] - v + part[blockIdx.x];
    if (i <= NN) rowptr[i] = excl;          // rowptr[NN] == EE
}

// ------ place: csr[rowptr[dst]+rank] = src; no atomics, fire-and-forget ------
__global__ void k_place(const int* __restrict__ src, const int* __restrict__ dst,
                        const int* __restrict__ rank, const int* __restrict__ rowptr,
                        int* __restrict__ csr) {
    int e = blockIdx.x * blockDim.x + threadIdx.x;
    if (e < EE)
        csr[rowptr[dst[e]] + rank[e]] = src[e];
}

// -- GEMM1 (reg-tiled): t1h = half2((x@W1)*dinv); tile 128r x 64c --
__global__ __launch_bounds__(256) void k_gemm1(const float* __restrict__ x,
        const float* __restrict__ W1, const int* __restrict__ cnt_in,
        __half2* __restrict__ t1h) {
    __shared__ float As[128][68];   // x-tile row-major [r][k], pad 64->68
    __shared__ float Bs[DD][DD];    // W1 [k][c]
    int t = threadIdx.x;
    int row0 = blockIdx.x * 128;
    #pragma unroll
    for (int j = 0; j < 4; ++j) {               // W1: 1024 float4
        int id = t + j * 256;
        int k = id >> 4, c4 = (id & 15) * 4;
        *(float4*)&Bs[k][c4] = *(const float4*)&W1[k * DD + c4];
    }
    #pragma unroll
    for (int j = 0; j < 8; ++j) {               // x-tile: 2048 float4
        int id = t + j * 256;
        int r = id >> 4, k4 = (id & 15) * 4;
        int gr = row0 + r;
        float4 v = make_float4(0.f, 0.f, 0.f, 0.f);
        if (gr < NN) v = *(const float4*)&x[gr * DD + k4];
        *(float4*)&As[r][k4] = v;
    }
    __syncthreads();
    int rbase = (t >> 3) * 4, cbase = (t & 7) * 8;
    float4 cL0 = make_float4(0.f,0.f,0.f,0.f), cH0 = cL0;
    float4 cL1 = cL0, cH1 = cL0, cL2 = cL0, cH2 = cL0, cL3 = cL0, cH3 = cL0;
    #pragma unroll 2
    for (int k = 0; k < DD; ++k) {
        float4 bL = *(const float4*)&Bs[k][cbase];
        float4 bH = *(const float4*)&Bs[k][cbase + 4];
        float a0 = As[rbase + 0][k];
        float a1 = As[rbase + 1][k];
        float a2 = As[rbase + 2][k];
        float a3 = As[rbase + 3][k];
        cL0 += bL * a0;  cH0 += bH * a0;
        cL1 += bL * a1;  cH1 += bH * a1;
        cL2 += bL * a2;  cH2 += bH * a2;
        cL3 += bL * a3;  cH3 += bH * a3;
    }
    int h2base = (t & 7) * 4;       // half2 index within row (32 half2/row)
    int gr0 = row0 + rbase;
    #define STORE_T1(idx, CL, CH) \
        if (gr0 + idx < NN) { \
            float d = rsqrtf((float)cnt_in[gr0 + idx] + 1.0f); \
            __half2 p0 = mk2(CL.x * d, CL.y * d), p1 = mk2(CL.z * d, CL.w * d); \
            __half2 p2 = mk2(CH.x * d, CH.y * d), p3 = mk2(CH.z * d, CH.w * d); \
            uint4 pk; pk.x = *(unsigned*)&p0; pk.y = *(unsigned*)&p1; \
            pk.z = *(unsigned*)&p2; pk.w = *(unsigned*)&p3; \
            *(uint4*)(t1h + (size_t)(gr0 + idx) * 32 + h2base) = pk; }
    STORE_T1(0, cL0, cH0)
    STORE_T1(1, cL1, cH1)
    STORE_T1(2, cL2, cH2)
    STORE_T1(3, cL3, cH3)
    #undef STORE_T1
}

// -- agg1 (half2 gather, half-wave per node): u = half2(dinv*relu(dinv*S + b1)) --
__global__ __launch_bounds__(256) void k_agg1(const int* __restrict__ rowptr,
        const int* __restrict__ csr, const __half2* __restrict__ t1h,
        const int* __restrict__ cnt_in, const float* __restrict__ b1,
        __half2* __restrict__ u_h) {
    int gid = blockIdx.x * blockDim.x + threadIdx.x;
    int node = gid >> 5;
    int p = threadIdx.x & 31;           // channel pair
    if (node >= NN) return;
    int beg = rowptr[node], end = rowptr[node + 1];
    float2 A0 = __half22float2(t1h[(size_t)node * 32 + p]);   // self-loop
    float2 A1 = make_float2(0.f, 0.f), A2 = A1, A3 = A1;
    int e = beg;
    for (; e + 4 <= end; e += 4) {
        int s0 = csr[e], s1 = csr[e + 1], s2 = csr[e + 2], s3 = csr[e + 3];
        float2 v0 = __half22float2(t1h[(size_t)s0 * 32 + p]);
        float2 v1 = __half22float2(t1h[(size_t)s1 * 32 + p]);
        float2 v2 = __half22float2(t1h[(size_t)s2 * 32 + p]);
        float2 v3 = __half22float2(t1h[(size_t)s3 * 32 + p]);
        A0.x += v0.x; A0.y += v0.y;
        A1.x += v1.x; A1.y += v1.y;
        A2.x += v2.x; A2.y += v2.y;
        A3.x += v3.x; A3.y += v3.y;
    }
    for (; e < end; ++e) {
        float2 v = __half22float2(t1h[(size_t)csr[e] * 32 + p]);
        A0.x += v.x; A0.y += v.y;
    }
    float sx = (A0.x + A1.x) + (A2.x + A3.x);
    float sy = (A0.y + A1.y) + (A2.y + A3.y);
    float d = rsqrtf((float)cnt_in[node] + 1.0f);
    float2 bb = ((const float2*)b1)[p];
    float h0 = fmaxf(d * sx + bb.x, 0.0f);
    float h1 = fmaxf(d * sy + bb.y, 0.0f);
    u_h[(size_t)node * 32 + p] = mk2(d * h0, d * h1);
}

// -- agg2 (half2 gather): w = dinv * (u[i] + Σ u[src]) (fp32 out for GEMM2) --
__global__ __launch_bounds__(256) void k_agg2(const int* __restrict__ rowptr,
        const int* __restrict__ csr, const __half2* __restrict__ u_h,
        const int* __restrict__ cnt_in, float* __restrict__ w) {
    int gid = blockIdx.x * blockDim.x + threadIdx.x;
    int node = gid >> 5;
    int p = threadIdx.x & 31;
    if (node >= NN) return;
    int beg = rowptr[node], end = rowptr[node + 1];
    float2 A0 = __half22float2(u_h[(size_t)node * 32 + p]);   // self-loop
    float2 A1 = make_float2(0.f, 0.f), A2 = A1, A3 = A1;
    int e = beg;
    for (; e + 4 <= end; e += 4) {
        int s0 = csr[e], s1 = csr[e + 1], s2 = csr[e + 2], s3 = csr[e + 3];
        float2 v0 = __half22float2(u_h[(size_t)s0 * 32 + p]);
        float2 v1 = __half22float2(u_h[(size_t)s1 * 32 + p]);
        float2 v2 = __half22float2(u_h[(size_t)s2 * 32 + p]);
        float2 v3 = __half22float2(u_h[(size_t)s3 * 32 + p]);
        A0.x += v0.x; A0.y += v0.y;
        A1.x += v1.x; A1.y += v1.y;
        A2.x += v2.x; A2.y += v2.y;
        A3.x += v3.x; A3.y += v3.y;
    }
    for (; e < end; ++e) {
        float2 v = __half22float2(u_h[(size_t)csr[e] * 32 + p]);
        A0.x += v.x; A0.y += v.y;
    }
    float d = rsqrtf((float)cnt_in[node] + 1.0f);
    float sx = (A0.x + A1.x) + (A2.x + A3.x);
    float sy = (A0.y + A1.y) + (A2.y + A3.y);
    ((float2*)&w[(size_t)node * DD])[p] = make_float2(d * sx, d * sy);
}

// -- GEMM2 (pure, reg-tiled): acc2 = w@W2 + b2; tile 64r x 128c --
__global__ __launch_bounds__(256) void k_gemm2(const float* __restrict__ w,
        const float* __restrict__ W2, const float* __restrict__ b2,
        float* __restrict__ acc2) {
    __shared__ float As[DD][68];    // w-tile row-major [r][k], pad 64->68
    __shared__ float Bs[DD][D2];    // W2 [k][c]
    int t = threadIdx.x;
    int row0 = blockIdx.x * 64;
    #pragma unroll
    for (int j = 0; j < 8; ++j) {               // W2: 2048 float4
        int id = t + j * 256;
        int k = id >> 5, c4 = (id & 31) * 4;
        *(float4*)&Bs[k][c4] = *(const float4*)&W2[k * D2 + c4];
    }
    #pragma unroll
    for (int j = 0; j < 4; ++j) {               // w-tile: 1024 float4
        int id = t + j * 256;
        int r = id >> 4, k4 = (id & 15) * 4;
        int gr = row0 + r;
        float4 v = make_float4(0.f, 0.f, 0.f, 0.f);
        if (gr < NN) v = *(const float4*)&w[gr * DD + k4];
        *(float4*)&As[r][k4] = v;
    }
    __syncthreads();
    int rbase = (t >> 4) * 4, cbase = (t & 15) * 8;
    float4 cL0 = make_float4(0.f,0.f,0.f,0.f), cH0 = cL0;
    float4 cL1 = cL0, cH1 = cL0, cL2 = cL0, cH2 = cL0, cL3 = cL0, cH3 = cL0;
    #pragma unroll 2
    for (int k = 0; k < DD; ++k) {
        float4 bL = *(const float4*)&Bs[k][cbase];
        float4 bH = *(const float4*)&Bs[k][cbase + 4];
        float a0 = As[rbase + 0][k];
        float a1 = As[rbase + 1][k];
        float a2 = As[rbase + 2][k];
        float a3 = As[rbase + 3][k];
        cL0 += bL * a0;  cH0 += bH * a0;
        cL1 += bL * a1;  cH1 += bH * a1;
        cL2 += bL * a2;  cH2 += bH * a2;
        cL3 += bL * a3;  cH3 += bH * a3;
    }
    float4 b2L = *(const float4*)&b2[cbase];
    float4 b2H = *(const float4*)&b2[cbase + 4];
    int gr0 = row0 + rbase;
    if (gr0 + 0 < NN) {
        *(float4*)&acc2[(gr0 + 0) * D2 + cbase] = cL0 + b2L;
        *(float4*)&acc2[(gr0 + 0) * D2 + cbase + 4] = cH0 + b2H; }
    if (gr0 + 1 < NN) {
        *(float4*)&acc2[(gr0 + 1) * D2 + cbase] = cL1 + b2L;
        *(float4*)&acc2[(gr0 + 1) * D2 + cbase + 4] = cH1 + b2H; }
    if (gr0 + 2 < NN) {
        *(float4*)&acc2[(gr0 + 2) * D2 + cbase] = cL2 + b2L;
        *(float4*)&acc2[(gr0 + 2) * D2 + cbase + 4] = cH2 + b2H; }
    if (gr0 + 3 < NN) {
        *(float4*)&acc2[(gr0 + 3) * D2 + cbase] = cL3 + b2L;
        *(float4*)&acc2[(gr0 + 3) * D2 + cbase + 4] = cH3 + b2H; }
}

// ------- pool2: per-graph mean (batch sorted; rows include b2) + fused FC ----
__global__ __launch_bounds__(128) void k_pool2(const float* __restrict__ acc2,
        const int* __restrict__ batch, const float* __restrict__ Wfc,
        const float* __restrict__ bfc, float* __restrict__ out) {
    int g = blockIdx.x;
    int t = threadIdx.x;                 // 0..127 = channel
    int lo = 0, hi = NN;
    while (lo < hi) { int mid = (lo + hi) >> 1; if (batch[mid] < g) lo = mid + 1; else hi = mid; }
    int beg = lo;
    hi = NN;
    while (lo < hi) { int mid = (lo + hi) >> 1; if (batch[mid] < g + 1) lo = mid + 1; else hi = mid; }
    int end = lo;

    float s0 = 0.0f, s1 = 0.0f;
    int i = beg;
    for (; i + 2 <= end; i += 2) {
        s0 += acc2[i * D2 + t];
        s1 += acc2[(i + 1) * D2 + t];
    }
    if (i < end) s0 += acc2[i * D2 + t];

    int n = end - beg;
    float pooledv = (n > 0) ? ((s0 + s1) / (float)n) : 0.0f;

    __shared__ float pm[D2];
    pm[t] = pooledv;
    __syncthreads();
    if (t < HIDD) {
        float o = bfc[t];
        #pragma unroll
        for (int k = 0; k < D2; ++k)
            o += pm[k] * Wfc[k * HIDD + t];
        out[g * HIDD + t] = o;
    }
}

extern "C" void kernel_launch(void* const* d_in, const int* in_sizes, int n_in,
                              void* d_out, int out_size, void* d_ws, size_t ws_size,
                              hipStream_t stream) {
    const float* x     = (const float*)d_in[0];
    const int*   ei    = (const int*)  d_in[1];
    const int*   batch = (const int*)  d_in[2];
    const float* W1    = (const float*)d_in[3];
    const float* b1    = (const float*)d_in[4];
    const float* W2    = (const float*)d_in[5];
    const float* b2    = (const float*)d_in[6];
    const float* Wfc   = (const float*)d_in[7];
    const float* bfc   = (const float*)d_in[8];
    float* out = (float*)d_out;

    const int* src = ei;
    const int* dst = ei + EE;

    // ---- workspace layout ----
    // [t1h 6.4MB][u_h 6.4MB][extra 12.8MB][w 12.8MB][ints]
    // acc2 (25.6MB) aliases [t1h, u_h, extra] — all dead by gemm2 time.
    char* base = (char*)d_ws;
    __half2* t1h  = (__half2*)base;                       // NN*32 half2
    __half2* u_h  = (__half2*)(base + (size_t)NN * 128);  // NN*32 half2
    float*   acc2 = (float*)base;                         // NN*128 f32 (alias)
    float*   w    = (float*)(base + (size_t)NN * 512);    // NN*64 f32
    int* iws    = (int*)(base + (size_t)NN * 512 + (size_t)NN * 256);
    int* cnt_in = iws;                          // NN
    int* rowptr = cnt_in + 50048;               // NN+1
    int* part   = rowptr + 50304;               // 256
    int* rank   = part + 256;                   // EE
    int* csr    = rank + EE;                    // EE
    // total ≈ 45 MB

    k_zero      <<<NBLK, 256, 0, stream>>>(cnt_in, part);
    k_count_rank<<<(EE + 255) / 256, 256, 0, stream>>>(dst, cnt_in, rank);
    k_partial   <<<NBLK, 256, 0, stream>>>(cnt_in, part);
    k_scanp     <<<1, 256, 0, stream>>>(part);
    k_rowptr    <<<NBLK, 256, 0, stream>>>(cnt_in, part, rowptr);
    k_place     <<<(EE + 255) / 256, 256, 0, stream>>>(src, dst, rank, rowptr, csr);
    k_gemm1     <<<(NN + 127) / 128, 256, 0, stream>>>(x, W1, cnt_in, t1h);
    k_agg1      <<<(NN * 32 + 255) / 256, 256, 0, stream>>>(rowptr, csr, t1h, cnt_in, b1, u_h);
    k_agg2      <<<(NN * 32 + 255) / 256, 256, 0, stream>>>(rowptr, csr, u_h, cnt_in, w);
    k_gemm2     <<<(NN + 63) / 64, 256, 0, stream>>>(w, W2, b2, acc2);
    k_pool2     <<<GG, 128, 0, stream>>>(acc2, batch, Wfc, bfc, out);
}

// Round 14
// 219.783 us; speedup vs baseline: 3.0804x; 1.0784x over previous
//
#include <hip/hip_runtime.h>
#include <hip/hip_fp16.h>

#define NN 50000
#define EE 800000
#define DD 64
#define GG 512
#define HIDD 64
#define D2 128
#define NBLK 196          // ceil(NN/256)

__device__ inline __half2 mk2(float a, float b) {
    __half2 h; h.x = __float2half_rn(a); h.y = __float2half_rn(b); return h;
}

// ---------------- zero: cnt_in[N], part[256] ----------------
__global__ void k_zero(int* __restrict__ cnt_in, int* __restrict__ part) {
    int i = blockIdx.x * blockDim.x + threadIdx.x;
    if (i < NN) cnt_in[i] = 0;
    if (i < 256) part[i] = 0;
}

// ------ count + rank: one atomic pass; rank stored coalesced ------
__global__ void k_count_rank(const int* __restrict__ dst, int* __restrict__ cnt_in,
                             int* __restrict__ rank) {
    int e = blockIdx.x * blockDim.x + threadIdx.x;
    if (e < EE) rank[e] = atomicAdd(&cnt_in[dst[e]], 1);
}

// ---------------- scan step 1: per-block sums ----------------
__global__ void k_partial(const int* __restrict__ cnt_in, int* __restrict__ part) {
    __shared__ int s[256];
    int t = threadIdx.x, i = blockIdx.x * 256 + t;
    s[t] = (i < NN) ? cnt_in[i] : 0;
    __syncthreads();
    for (int off = 128; off > 0; off >>= 1) {
        if (t < off) s[t] += s[t + off];
        __syncthreads();
    }
    if (t == 0) part[blockIdx.x] = s[0];
}

// ---------------- scan step 2: exclusive scan of 256 partials ----------------
__global__ void k_scanp(int* __restrict__ part) {
    __shared__ int s[256];
    int t = threadIdx.x;
    int v = part[t];
    s[t] = v;
    __syncthreads();
    for (int off = 1; off < 256; off <<= 1) {
        int add = (t >= off) ? s[t - off] : 0;
        __syncthreads();
        s[t] += add;
        __syncthreads();
    }
    part[t] = s[t] - v;     // exclusive
}

// ---------------- scan step 3: rowptr ----------------
__global__ void k_rowptr(const int* __restrict__ cnt_in, const int* __restrict__ part,
                         int* __restrict__ rowptr) {
    __shared__ int s[256];
    int t = threadIdx.x, i = blockIdx.x * 256 + t;
    int v = (i < NN) ? cnt_in[i] : 0;
    s[t] = v;
    __syncthreads();
    for (int off = 1; off < 256; off <<= 1) {
        int add = (t >= off) ? s[t - off] : 0;
        __syncthreads();
        s[t] += add;
        __syncthreads();
    }
    int excl = s[t] - v + part[blockIdx.x];
    if (i <= NN) rowptr[i] = excl;          // rowptr[NN] == EE
}

// ------ place: csr[rowptr[dst]+rank] = src; no atomics, fire-and-forget ------
__global__ void k_place(const int* __restrict__ src, const int* __restrict__ dst,
                        const int* __restrict__ rank, const int* __restrict__ rowptr,
                        int* __restrict__ csr) {
    int e = blockIdx.x * blockDim.x + threadIdx.x;
    if (e < EE)
        csr[rowptr[dst[e]] + rank[e]] = src[e];
}

// -- GEMM1 (reg-tiled): t1h = half2((x@W1)*dinv); tile 128r x 64c --
__global__ __launch_bounds__(256) void k_gemm1(const float* __restrict__ x,
        const float* __restrict__ W1, const int* __restrict__ cnt_in,
        __half2* __restrict__ t1h) {
    __shared__ float As[128][68];   // x-tile row-major [r][k], pad 64->68
    __shared__ float Bs[DD][DD];    // W1 [k][c]
    int t = threadIdx.x;
    int row0 = blockIdx.x * 128;
    #pragma unroll
    for (int j = 0; j < 4; ++j) {               // W1: 1024 float4
        int id = t + j * 256;
        int k = id >> 4, c4 = (id & 15) * 4;
        *(float4*)&Bs[k][c4] = *(const float4*)&W1[k * DD + c4];
    }
    #pragma unroll
    for (int j = 0; j < 8; ++j) {               // x-tile: 2048 float4
        int id = t + j * 256;
        int r = id >> 4, k4 = (id & 15) * 4;
        int gr = row0 + r;
        float4 v = make_float4(0.f, 0.f, 0.f, 0.f);
        if (gr < NN) v = *(const float4*)&x[gr * DD + k4];
        *(float4*)&As[r][k4] = v;
    }
    __syncthreads();
    int rbase = (t >> 3) * 4, cbase = (t & 7) * 8;
    float4 cL0 = make_float4(0.f,0.f,0.f,0.f), cH0 = cL0;
    float4 cL1 = cL0, cH1 = cL0, cL2 = cL0, cH2 = cL0, cL3 = cL0, cH3 = cL0;
    #pragma unroll 2
    for (int k = 0; k < DD; ++k) {
        float4 bL = *(const float4*)&Bs[k][cbase];
        float4 bH = *(const float4*)&Bs[k][cbase + 4];
        float a0 = As[rbase + 0][k];
        float a1 = As[rbase + 1][k];
        float a2 = As[rbase + 2][k];
        float a3 = As[rbase + 3][k];
        cL0 += bL * a0;  cH0 += bH * a0;
        cL1 += bL * a1;  cH1 += bH * a1;
        cL2 += bL * a2;  cH2 += bH * a2;
        cL3 += bL * a3;  cH3 += bH * a3;
    }
    int h2base = (t & 7) * 4;       // half2 index within row (32 half2/row)
    int gr0 = row0 + rbase;
    #define STORE_T1(idx, CL, CH) \
        if (gr0 + idx < NN) { \
            float d = rsqrtf((float)cnt_in[gr0 + idx] + 1.0f); \
            __half2 p0 = mk2(CL.x * d, CL.y * d), p1 = mk2(CL.z * d, CL.w * d); \
            __half2 p2 = mk2(CH.x * d, CH.y * d), p3 = mk2(CH.z * d, CH.w * d); \
            uint4 pk; pk.x = *(unsigned*)&p0; pk.y = *(unsigned*)&p1; \
            pk.z = *(unsigned*)&p2; pk.w = *(unsigned*)&p3; \
            *(uint4*)(t1h + (size_t)(gr0 + idx) * 32 + h2base) = pk; }
    STORE_T1(0, cL0, cH0)
    STORE_T1(1, cL1, cH1)
    STORE_T1(2, cL2, cH2)
    STORE_T1(3, cL3, cH3)
    #undef STORE_T1
}

// -- agg1 (half2 gather, half-wave per node): u = half2(dinv*relu(dinv*S + b1)) --
__global__ __launch_bounds__(256) void k_agg1(const int* __restrict__ rowptr,
        const int* __restrict__ csr, const __half2* __restrict__ t1h,
        const int* __restrict__ cnt_in, const float* __restrict__ b1,
        __half2* __restrict__ u_h) {
    int gid = blockIdx.x * blockDim.x + threadIdx.x;
    int node = gid >> 5;
    int p = threadIdx.x & 31;           // channel pair
    if (node >= NN) return;
    int beg = rowptr[node], end = rowptr[node + 1];
    float2 A0 = __half22float2(t1h[(size_t)node * 32 + p]);   // self-loop
    float2 A1 = make_float2(0.f, 0.f), A2 = A1, A3 = A1;
    int e = beg;
    for (; e + 4 <= end; e += 4) {
        int s0 = csr[e], s1 = csr[e + 1], s2 = csr[e + 2], s3 = csr[e + 3];
        float2 v0 = __half22float2(t1h[(size_t)s0 * 32 + p]);
        float2 v1 = __half22float2(t1h[(size_t)s1 * 32 + p]);
        float2 v2 = __half22float2(t1h[(size_t)s2 * 32 + p]);
        float2 v3 = __half22float2(t1h[(size_t)s3 * 32 + p]);
        A0.x += v0.x; A0.y += v0.y;
        A1.x += v1.x; A1.y += v1.y;
        A2.x += v2.x; A2.y += v2.y;
        A3.x += v3.x; A3.y += v3.y;
    }
    for (; e < end; ++e) {
        float2 v = __half22float2(t1h[(size_t)csr[e] * 32 + p]);
        A0.x += v.x; A0.y += v.y;
    }
    float sx = (A0.x + A1.x) + (A2.x + A3.x);
    float sy = (A0.y + A1.y) + (A2.y + A3.y);
    float d = rsqrtf((float)cnt_in[node] + 1.0f);
    float2 bb = ((const float2*)b1)[p];
    float h0 = fmaxf(d * sx + bb.x, 0.0f);
    float h1 = fmaxf(d * sy + bb.y, 0.0f);
    u_h[(size_t)node * 32 + p] = mk2(d * h0, d * h1);
}

// -- agg2 (half2 gather): w = dinv * (u[i] + Σ u[src]) (fp32 out) --
__global__ __launch_bounds__(256) void k_agg2(const int* __restrict__ rowptr,
        const int* __restrict__ csr, const __half2* __restrict__ u_h,
        const int* __restrict__ cnt_in, float* __restrict__ w) {
    int gid = blockIdx.x * blockDim.x + threadIdx.x;
    int node = gid >> 5;
    int p = threadIdx.x & 31;
    if (node >= NN) return;
    int beg = rowptr[node], end = rowptr[node + 1];
    float2 A0 = __half22float2(u_h[(size_t)node * 32 + p]);   // self-loop
    float2 A1 = make_float2(0.f, 0.f), A2 = A1, A3 = A1;
    int e = beg;
    for (; e + 4 <= end; e += 4) {
        int s0 = csr[e], s1 = csr[e + 1], s2 = csr[e + 2], s3 = csr[e + 3];
        float2 v0 = __half22float2(u_h[(size_t)s0 * 32 + p]);
        float2 v1 = __half22float2(u_h[(size_t)s1 * 32 + p]);
        float2 v2 = __half22float2(u_h[(size_t)s2 * 32 + p]);
        float2 v3 = __half22float2(u_h[(size_t)s3 * 32 + p]);
        A0.x += v0.x; A0.y += v0.y;
        A1.x += v1.x; A1.y += v1.y;
        A2.x += v2.x; A2.y += v2.y;
        A3.x += v3.x; A3.y += v3.y;
    }
    for (; e < end; ++e) {
        float2 v = __half22float2(u_h[(size_t)csr[e] * 32 + p]);
        A0.x += v.x; A0.y += v.y;
    }
    float d = rsqrtf((float)cnt_in[node] + 1.0f);
    float sx = (A0.x + A1.x) + (A2.x + A3.x);
    float sy = (A0.y + A1.y) + (A2.y + A3.y);
    ((float2*)&w[(size_t)node * DD])[p] = make_float2(d * sx, d * sy);
}

// -- pool + fused W2/Wfc chain: out[g] = (mean_{i∈g} w[i] @ W2 + b2) @ Wfc + bfc
// (mean pushed through the linear layer; empty graphs -> out = bfc)
__global__ __launch_bounds__(128) void k_pool2(const float* __restrict__ w,
        const int* __restrict__ batch, const float* __restrict__ W2,
        const float* __restrict__ b2, const float* __restrict__ Wfc,
        const float* __restrict__ bfc, float* __restrict__ out) {
    int g = blockIdx.x;
    int t = threadIdx.x;                 // 128 threads
    int c = t & 63, half = t >> 6;
    // segment [beg,end) of sorted batch
    int lo = 0, hi = NN;
    while (lo < hi) { int mid = (lo + hi) >> 1; if (batch[mid] < g) lo = mid + 1; else hi = mid; }
    int beg = lo;
    hi = NN;
    while (lo < hi) { int mid = (lo + hi) >> 1; if (batch[mid] < g + 1) lo = mid + 1; else hi = mid; }
    int end = lo;
    int n = end - beg;

    float s = 0.0f;
    for (int i = beg + half; i < end; i += 2)
        s += w[(size_t)i * DD + c];

    __shared__ float sm[128];
    __shared__ float pm[DD];
    __shared__ float tt[D2];
    sm[t] = s;
    __syncthreads();
    if (t < DD) {
        float scale = (n > 0) ? (1.0f / (float)n) : 0.0f;
        pm[t] = (sm[t] + sm[t + 64]) * scale;
    }
    __syncthreads();
    // tt = pm @ W2 (+ b2 if non-empty)
    {
        float acc = (n > 0) ? b2[t] : 0.0f;
        #pragma unroll 4
        for (int k = 0; k < DD; ++k)
            acc += pm[k] * W2[k * D2 + t];
        tt[t] = acc;
    }
    __syncthreads();
    if (t < HIDD) {
        float o = bfc[t];
        #pragma unroll 4
        for (int k = 0; k < D2; ++k)
            o += tt[k] * Wfc[k * HIDD + t];
        out[g * HIDD + t] = o;
    }
}

extern "C" void kernel_launch(void* const* d_in, const int* in_sizes, int n_in,
                              void* d_out, int out_size, void* d_ws, size_t ws_size,
                              hipStream_t stream) {
    const float* x     = (const float*)d_in[0];
    const int*   ei    = (const int*)  d_in[1];
    const int*   batch = (const int*)  d_in[2];
    const float* W1    = (const float*)d_in[3];
    const float* b1    = (const float*)d_in[4];
    const float* W2    = (const float*)d_in[5];
    const float* b2    = (const float*)d_in[6];
    const float* Wfc   = (const float*)d_in[7];
    const float* bfc   = (const float*)d_in[8];
    float* out = (float*)d_out;

    const int* src = ei;
    const int* dst = ei + EE;

    // ---- workspace layout (unchanged offsets from R13) ----
    char* base = (char*)d_ws;
    __half2* t1h  = (__half2*)base;                       // NN*32 half2
    __half2* u_h  = (__half2*)(base + (size_t)NN * 128);  // NN*32 half2
    float*   w    = (float*)(base + (size_t)NN * 512);    // NN*64 f32
    int* iws    = (int*)(base + (size_t)NN * 512 + (size_t)NN * 256);
    int* cnt_in = iws;                          // NN
    int* rowptr = cnt_in + 50048;               // NN+1
    int* part   = rowptr + 50304;               // 256
    int* rank   = part + 256;                   // EE
    int* csr    = rank + EE;                    // EE

    k_zero      <<<NBLK, 256, 0, stream>>>(cnt_in, part);
    k_count_rank<<<(EE + 255) / 256, 256, 0, stream>>>(dst, cnt_in, rank);
    k_partial   <<<NBLK, 256, 0, stream>>>(cnt_in, part);
    k_scanp     <<<1, 256, 0, stream>>>(part);
    k_rowptr    <<<NBLK, 256, 0, stream>>>(cnt_in, part, rowptr);
    k_place     <<<(EE + 255) / 256, 256, 0, stream>>>(src, dst, rank, rowptr, csr);
    k_gemm1     <<<(NN + 127) / 128, 256, 0, stream>>>(x, W1, cnt_in, t1h);
    k_agg1      <<<(NN * 32 + 255) / 256, 256, 0, stream>>>(rowptr, csr, t1h, cnt_in, b1, u_h);
    k_agg2      <<<(NN * 32 + 255) / 256, 256, 0, stream>>>(rowptr, csr, u_h, cnt_in, w);
    k_pool2     <<<GG, 128, 0, stream>>>(w, batch, W2, b2, Wfc, bfc, out);
}